// Round 1
// baseline (940.350 us; speedup 1.0000x reference)
//
#include <hip/hip_runtime.h>

#define N_NODES 100000
#define N_EDGES 1600000
#define N_GRAPHS 512

// ---------------- CSR build ----------------

__global__ __launch_bounds__(256) void hist_kernel(const int* __restrict__ dst,
                                                   int* __restrict__ cnt) {
    int e = blockIdx.x * 256 + threadIdx.x;
    if (e < N_EDGES) atomicAdd(&cnt[dst[e]], 1);
}

// single-block exclusive scan over cnt[0..n), writes off[0..n], and cnt becomes cursor(=off copy)
__global__ __launch_bounds__(1024) void scan_kernel(int* __restrict__ cnt,
                                                    int* __restrict__ off, int n) {
    __shared__ int wsums[16];
    __shared__ int s_carry;
    int tid = threadIdx.x;
    if (tid == 0) s_carry = 0;
    __syncthreads();
    int nChunks = (n + 1023) >> 10;
    for (int ch = 0; ch < nChunks; ++ch) {
        int i = (ch << 10) + tid;
        int v = (i < n) ? cnt[i] : 0;
        int lane = tid & 63;
        int w = tid >> 6;
        int incl = v;
        #pragma unroll
        for (int s = 1; s < 64; s <<= 1) {
            int y = __shfl_up(incl, s, 64);
            if (lane >= s) incl += y;
        }
        if (lane == 63) wsums[w] = incl;
        __syncthreads();
        if (tid < 16) {
            int t = wsums[tid];
            #pragma unroll
            for (int s = 1; s < 16; s <<= 1) {
                int y = __shfl_up(t, s, 64);
                if (tid >= s) t += y;
            }
            wsums[tid] = t;  // inclusive scan of wave sums
        }
        __syncthreads();
        int wpref = (w == 0) ? 0 : wsums[w - 1];
        int excl = s_carry + wpref + incl - v;
        if (i < n) { off[i] = excl; cnt[i] = excl; }
        int blocktotal = wsums[15];
        __syncthreads();
        if (tid == 0) s_carry += blocktotal;
        __syncthreads();
    }
    if (tid == 0) off[n] = s_carry;
}

__global__ __launch_bounds__(256) void fill_kernel(const int* __restrict__ src,
                                                   const int* __restrict__ dst,
                                                   int* __restrict__ cursor,
                                                   int* __restrict__ srclist) {
    int e = blockIdx.x * 256 + threadIdx.x;
    if (e < N_EDGES) {
        int p = atomicAdd(&cursor[dst[e]], 1);
        srclist[p] = src[e];
    }
}

// ---------------- pull-mode aggregation: A[n] = sum_{j in N(n)} X[src_j] ----------------

__global__ __launch_bounds__(256) void agg_kernel(const float4* __restrict__ X4,
                                                  float4* __restrict__ A4,
                                                  const int* __restrict__ off,
                                                  const int* __restrict__ srclist) {
    int t = blockIdx.x * 256 + threadIdx.x;
    int n = t >> 5;
    int c = t & 31;
    if (n >= N_NODES) return;
    int j0 = off[n], j1 = off[n + 1];
    float4 acc = make_float4(0.f, 0.f, 0.f, 0.f);
    for (int j = j0; j < j1; ++j) {
        int s = srclist[j];  // broadcast within 32-lane group
        float4 vv = X4[s * 32 + c];
        acc.x += vv.x; acc.y += vv.y; acc.z += vv.z; acc.w += vv.w;
    }
    A4[n * 32 + c] = acc;
}

// ---------------- W transpose (Wt[k][f] = W[f][k]) ----------------

__global__ __launch_bounds__(128) void transpose_kernel(const float* __restrict__ W,
                                                        float* __restrict__ Wt) {
    int f = blockIdx.x;    // 0..127
    int k = threadIdx.x;   // 0..127
    Wt[k * 128 + f] = W[f * 128 + k];
}

// ---------------- H[n] = act((X[n]+A[n]) @ Wt + b) ----------------
// block: 256 threads, 64 nodes. fg = tid&15 covers features {fg*4..fg*4+3, 64+fg*4..+3}
// ngp = tid>>4 covers nodes {ngp*4..ngp*4+3}. In-place safe (X==H): block reads its own
// rows into LDS before writing them.

__global__ __launch_bounds__(256) void gemm_kernel(const float* __restrict__ X,
                                                   const float* __restrict__ Ag,
                                                   const float* __restrict__ Wt,
                                                   const float* __restrict__ bias,
                                                   float* __restrict__ H, int doRelu) {
    __shared__ float v[64 * 132];
    int tid = threadIdx.x;
    int n0 = blockIdx.x * 64;
    const float4* X4 = (const float4*)X;
    const float4* A4 = (const float4*)Ag;
    #pragma unroll
    for (int i = 0; i < 8; ++i) {
        int fidx = i * 256 + tid;     // 0..2047 float4 slots
        int r = fidx >> 5;            // row 0..63
        int c4 = fidx & 31;
        int n = n0 + r;
        float4 val = make_float4(0.f, 0.f, 0.f, 0.f);
        if (n < N_NODES) {
            float4 a = X4[n * 32 + c4];
            float4 b = A4[n * 32 + c4];
            val = make_float4(a.x + b.x, a.y + b.y, a.z + b.z, a.w + b.w);
        }
        *(float4*)&v[r * 132 + c4 * 4] = val;
    }
    __syncthreads();

    int fg = tid & 15;
    int ngp = tid >> 4;
    const float4* Wt4 = (const float4*)Wt;
    float acc[4][8];
    #pragma unroll
    for (int i = 0; i < 4; ++i)
        #pragma unroll
        for (int j = 0; j < 8; ++j) acc[i][j] = 0.f;

    #pragma unroll 4
    for (int k = 0; k < 128; ++k) {
        float4 w0 = Wt4[k * 32 + fg];
        float4 w1 = Wt4[k * 32 + 16 + fg];
        float vv[4];
        #pragma unroll
        for (int i = 0; i < 4; ++i) vv[i] = v[(ngp * 4 + i) * 132 + k];
        #pragma unroll
        for (int i = 0; i < 4; ++i) {
            acc[i][0] += vv[i] * w0.x; acc[i][1] += vv[i] * w0.y;
            acc[i][2] += vv[i] * w0.z; acc[i][3] += vv[i] * w0.w;
            acc[i][4] += vv[i] * w1.x; acc[i][5] += vv[i] * w1.y;
            acc[i][6] += vv[i] * w1.z; acc[i][7] += vv[i] * w1.w;
        }
    }

    float4 ba = ((const float4*)bias)[fg];
    float4 bb = ((const float4*)bias)[16 + fg];
    float4* H4 = (float4*)H;
    #pragma unroll
    for (int i = 0; i < 4; ++i) {
        int n = n0 + ngp * 4 + i;
        if (n >= N_NODES) continue;
        float4 o0 = make_float4(acc[i][0] + ba.x, acc[i][1] + ba.y,
                                acc[i][2] + ba.z, acc[i][3] + ba.w);
        float4 o1 = make_float4(acc[i][4] + bb.x, acc[i][5] + bb.y,
                                acc[i][6] + bb.z, acc[i][7] + bb.w);
        if (doRelu) {
            o0.x = fmaxf(o0.x, 0.f); o0.y = fmaxf(o0.y, 0.f);
            o0.z = fmaxf(o0.z, 0.f); o0.w = fmaxf(o0.w, 0.f);
            o1.x = fmaxf(o1.x, 0.f); o1.y = fmaxf(o1.y, 0.f);
            o1.z = fmaxf(o1.z, 0.f); o1.w = fmaxf(o1.w, 0.f);
        }
        H4[n * 32 + fg] = o0;
        H4[n * 32 + 16 + fg] = o1;
    }
}

// ---------------- pooling + final linear ----------------

__device__ __forceinline__ int lower_bound_i(const int* a, int n, int val) {
    int lo = 0, hi = n;
    while (lo < hi) {
        int mid = (lo + hi) >> 1;
        if (a[mid] < val) lo = mid + 1; else hi = mid;
    }
    return lo;
}

__global__ __launch_bounds__(128) void pool_kernel(const float* __restrict__ H,
                                                   const int* __restrict__ batch,
                                                   const float* __restrict__ Wg,
                                                   const float* __restrict__ bg,
                                                   float* __restrict__ out) {
    int g = blockIdx.x;       // 0..511
    int f = threadIdx.x;      // 0..127
    int lo = lower_bound_i(batch, N_NODES, g);
    int hi = lower_bound_i(batch, N_NODES, g + 1);
    float acc = 0.f;
    for (int i = lo; i < hi; ++i) acc += H[(size_t)i * 128 + f];
    float cntf = (float)(hi - lo);
    float pooled = acc / fmaxf(cntf, 1.0f);
    __shared__ float p[128];
    p[f] = pooled;
    __syncthreads();
    if (f < 10) {
        float s = bg[f];
        #pragma unroll 4
        for (int k = 0; k < 128; ++k) s += p[k] * Wg[f * 128 + k];
        out[g * 10 + f] = s;
    }
}

// ---------------- launch ----------------

extern "C" void kernel_launch(void* const* d_in, const int* in_sizes, int n_in,
                              void* d_out, int out_size, void* d_ws, size_t ws_size,
                              hipStream_t stream) {
    const float* x   = (const float*)d_in[0];
    const int*   ei  = (const int*)d_in[1];
    const int*   bat = (const int*)d_in[2];
    const float* W0  = (const float*)d_in[3];
    const float* b0  = (const float*)d_in[4];
    const float* W1  = (const float*)d_in[5];
    const float* b1  = (const float*)d_in[6];
    const float* W2  = (const float*)d_in[7];
    const float* b2  = (const float*)d_in[8];
    const float* Wg  = (const float*)d_in[9];
    const float* bg  = (const float*)d_in[10];
    float* out = (float*)d_out;

    const int* src = ei;
    const int* dst = ei + N_EDGES;

    char* w = (char*)d_ws;
    float* A   = (float*)(w);                               // 51,200,000 B
    float* H   = (float*)(w + 51200000);                    // 51,200,000 B
    float* Wt0 = (float*)(w + 102400000);                   // 64 KiB
    float* Wt1 = Wt0 + 16384;
    float* Wt2 = Wt1 + 16384;
    int* cnt     = (int*)(w + 102400000 + 3 * 65536);       // N_NODES ints (counts -> cursor)
    int* off     = cnt + N_NODES;                           // N_NODES+1 ints
    int* srclist = off + N_NODES + 2;                       // N_EDGES ints

    // CSR build (once; shared by all 3 layers)
    hipMemsetAsync(cnt, 0, N_NODES * sizeof(int), stream);
    hist_kernel<<<(N_EDGES + 255) / 256, 256, 0, stream>>>(dst, cnt);
    scan_kernel<<<1, 1024, 0, stream>>>(cnt, off, N_NODES);
    fill_kernel<<<(N_EDGES + 255) / 256, 256, 0, stream>>>(src, dst, cnt, srclist);

    // weight transposes
    transpose_kernel<<<128, 128, 0, stream>>>(W0, Wt0);
    transpose_kernel<<<128, 128, 0, stream>>>(W1, Wt1);
    transpose_kernel<<<128, 128, 0, stream>>>(W2, Wt2);

    int aggGrid  = (N_NODES * 32 + 255) / 256;
    int gemmGrid = (N_NODES + 63) / 64;

    // layer 0
    agg_kernel<<<aggGrid, 256, 0, stream>>>((const float4*)x, (float4*)A, off, srclist);
    gemm_kernel<<<gemmGrid, 256, 0, stream>>>(x, A, Wt0, b0, H, 1);
    // layer 1
    agg_kernel<<<aggGrid, 256, 0, stream>>>((const float4*)H, (float4*)A, off, srclist);
    gemm_kernel<<<gemmGrid, 256, 0, stream>>>(H, A, Wt1, b1, H, 1);
    // layer 2
    agg_kernel<<<aggGrid, 256, 0, stream>>>((const float4*)H, (float4*)A, off, srclist);
    gemm_kernel<<<gemmGrid, 256, 0, stream>>>(H, A, Wt2, b2, H, 0);

    // pool + classifier
    pool_kernel<<<N_GRAPHS, 128, 0, stream>>>(H, bat, Wg, bg, out);
}

// Round 2
// 479.245 us; speedup vs baseline: 1.9621x; 1.9621x over previous
//
#include <hip/hip_runtime.h>

#define N_NODES 100000
#define N_EDGES 1600000
#define N_GRAPHS 512
#define NBUCK 391          // ceil(N_NODES / 256)
#define EPB 8192           // edges per block for bucket passes
#define NB_BIN ((N_EDGES + EPB - 1) / EPB)   // 196
#define CAP 5120           // LDS staging capacity per bucket (mean 4096, sd 64)

// ---------- bf16 helpers ----------
__device__ __forceinline__ unsigned short f2b(float f) {
    unsigned u = __float_as_uint(f);
    unsigned r = u + 0x7fffu + ((u >> 16) & 1u);
    return (unsigned short)(r >> 16);
}
__device__ __forceinline__ void addbf(float* acc, uint4 u) {
    acc[0] += __uint_as_float(u.x << 16); acc[1] += __uint_as_float(u.x & 0xffff0000u);
    acc[2] += __uint_as_float(u.y << 16); acc[3] += __uint_as_float(u.y & 0xffff0000u);
    acc[4] += __uint_as_float(u.z << 16); acc[5] += __uint_as_float(u.z & 0xffff0000u);
    acc[6] += __uint_as_float(u.w << 16); acc[7] += __uint_as_float(u.w & 0xffff0000u);
}

// ---------- CSR build: 2-level counting sort ----------

__global__ __launch_bounds__(256) void bucket_hist(const int* __restrict__ dst,
                                                   int* __restrict__ gcnt) {
    __shared__ int c[NBUCK];
    int tid = threadIdx.x;
    for (int i = tid; i < NBUCK; i += 256) c[i] = 0;
    __syncthreads();
    int e0 = blockIdx.x * EPB, e1 = min(e0 + EPB, N_EDGES);
    for (int e = e0 + tid; e < e1; e += 256) atomicAdd(&c[dst[e] >> 8], 1);
    __syncthreads();
    for (int i = tid; i < NBUCK; i += 256) { int v = c[i]; if (v) atomicAdd(&gcnt[i], v); }
}

__global__ __launch_bounds__(512) void bucket_scan(const int* __restrict__ gcnt,
                                                   int* __restrict__ boff,
                                                   int* __restrict__ gcur,
                                                   int* __restrict__ off) {
    __shared__ int ws[8];
    int tid = threadIdx.x;
    int v = (tid < NBUCK) ? gcnt[tid] : 0;
    int lane = tid & 63, w = tid >> 6;
    int incl = v;
    #pragma unroll
    for (int s = 1; s < 64; s <<= 1) { int y = __shfl_up(incl, s, 64); if (lane >= s) incl += y; }
    if (lane == 63) ws[w] = incl;
    __syncthreads();
    if (tid < 8) {
        int t = ws[tid];
        #pragma unroll
        for (int s = 1; s < 8; s <<= 1) { int y = __shfl_up(t, s, 64); if (tid >= s) t += y; }
        ws[tid] = t;
    }
    __syncthreads();
    int excl = (w ? ws[w - 1] : 0) + incl - v;
    if (tid < NBUCK) { boff[tid] = excl; gcur[tid] = excl; }
    if (tid == NBUCK - 1) boff[NBUCK] = excl + v;
    if (tid == 0) off[N_NODES] = N_EDGES;
}

__global__ __launch_bounds__(256) void bucket_scatter(const int* __restrict__ src,
                                                      const int* __restrict__ dst,
                                                      int* __restrict__ gcur,
                                                      int2* __restrict__ pairs) {
    __shared__ int cnt[NBUCK];
    __shared__ int base[NBUCK];
    int tid = threadIdx.x;
    for (int i = tid; i < NBUCK; i += 256) cnt[i] = 0;
    __syncthreads();
    int e0 = blockIdx.x * EPB, e1 = min(e0 + EPB, N_EDGES);
    for (int e = e0 + tid; e < e1; e += 256) atomicAdd(&cnt[dst[e] >> 8], 1);
    __syncthreads();
    for (int i = tid; i < NBUCK; i += 256) {
        int v = cnt[i];
        base[i] = v ? atomicAdd(&gcur[i], v) : 0;
        cnt[i] = 0;
    }
    __syncthreads();
    for (int e = e0 + tid; e < e1; e += 256) {
        int d = dst[e], b = d >> 8;
        int r = atomicAdd(&cnt[b], 1);
        pairs[base[b] + r] = make_int2(src[e], d);
    }
}

__global__ __launch_bounds__(256) void bucket_fine(const int2* __restrict__ pairs,
                                                   const int* __restrict__ boff,
                                                   int* __restrict__ off,
                                                   int* __restrict__ srclist) {
    __shared__ int ncnt[256];
    __shared__ int ws[4];
    __shared__ int stage[CAP];
    int tid = threadIdx.x, b = blockIdx.x;
    int eLo = boff[b], eHi = boff[b + 1], m = eHi - eLo;
    ncnt[tid] = 0;
    __syncthreads();
    for (int t = tid; t < m; t += 256) {
        int2 p = pairs[eLo + t];
        atomicAdd(&ncnt[p.y & 255], 1);
    }
    __syncthreads();
    int v = ncnt[tid];
    int lane = tid & 63, w = tid >> 6;
    int incl = v;
    #pragma unroll
    for (int s = 1; s < 64; s <<= 1) { int y = __shfl_up(incl, s, 64); if (lane >= s) incl += y; }
    if (lane == 63) ws[w] = incl;
    __syncthreads();
    if (tid < 4) {
        int t = ws[tid];
        #pragma unroll
        for (int s = 1; s < 4; s <<= 1) { int y = __shfl_up(t, s, 64); if (tid >= s) t += y; }
        ws[tid] = t;
    }
    __syncthreads();
    int excl = (w ? ws[w - 1] : 0) + incl - v;
    int n = (b << 8) + tid;
    if (n < N_NODES) off[n] = eLo + excl;
    __syncthreads();
    ncnt[tid] = excl;   // becomes cursor
    __syncthreads();
    for (int t = tid; t < m; t += 256) {
        int2 p = pairs[eLo + t];
        int r = atomicAdd(&ncnt[p.y & 255], 1);
        if (r < CAP) stage[r] = p.x;
        else srclist[eLo + r] = p.x;
    }
    __syncthreads();
    int lim = m < CAP ? m : CAP;
    for (int t = tid; t < lim; t += 256) srclist[eLo + t] = stage[t];
}

// ---------- fp32 -> bf16 convert (x -> Xb) ----------
__global__ __launch_bounds__(256) void convert_bf16(const float4* __restrict__ X4,
                                                    uint4* __restrict__ Xb) {
    int t = blockIdx.x * 256 + threadIdx.x;
    if (t >= N_NODES * 16) return;
    float4 a = X4[t * 2], b = X4[t * 2 + 1];
    uint4 o;
    o.x = (unsigned)f2b(a.x) | ((unsigned)f2b(a.y) << 16);
    o.y = (unsigned)f2b(a.z) | ((unsigned)f2b(a.w) << 16);
    o.z = (unsigned)f2b(b.x) | ((unsigned)f2b(b.y) << 16);
    o.w = (unsigned)f2b(b.z) | ((unsigned)f2b(b.w) << 16);
    Xb[t] = o;
}

// ---------- pull aggregation (bf16 gather, fp32 accum): A[n] = X[n] + sum_j X[src_j] ----------
__global__ __launch_bounds__(256) void agg_bf16(const uint4* __restrict__ Xb,
                                                float* __restrict__ A,
                                                const int* __restrict__ off,
                                                const int* __restrict__ srclist) {
    int t = blockIdx.x * 256 + threadIdx.x;
    int n = t >> 4, c = t & 15;
    if (n >= N_NODES) return;
    int j0 = off[n], j1 = off[n + 1];
    float acc[8] = {0, 0, 0, 0, 0, 0, 0, 0};
    addbf(acc, Xb[n * 16 + c]);   // own row (GIN eps=0)
    int j = j0;
    for (; j + 3 < j1; j += 4) {
        int s0 = srclist[j], s1 = srclist[j + 1], s2 = srclist[j + 2], s3 = srclist[j + 3];
        uint4 v0 = Xb[s0 * 16 + c];
        uint4 v1 = Xb[s1 * 16 + c];
        uint4 v2 = Xb[s2 * 16 + c];
        uint4 v3 = Xb[s3 * 16 + c];
        addbf(acc, v0); addbf(acc, v1); addbf(acc, v2); addbf(acc, v3);
    }
    for (; j < j1; ++j) {
        int s = srclist[j];
        addbf(acc, Xb[s * 16 + c]);
    }
    float4* A4 = (float4*)A;
    A4[n * 32 + c * 2]     = make_float4(acc[0], acc[1], acc[2], acc[3]);
    A4[n * 32 + c * 2 + 1] = make_float4(acc[4], acc[5], acc[6], acc[7]);
}

// ---------- W transpose ----------
__global__ __launch_bounds__(128) void transpose_kernel(const float* __restrict__ W,
                                                        float* __restrict__ Wt) {
    int f = blockIdx.x, k = threadIdx.x;
    Wt[k * 128 + f] = W[f * 128 + k];
}

// ---------- H[n] = act(A[n] @ Wt + b), output bf16 ----------
__global__ __launch_bounds__(256) void gemm_kernel(const float* __restrict__ Ag,
                                                   const float* __restrict__ Wt,
                                                   const float* __restrict__ bias,
                                                   ushort4* __restrict__ Hb, int doRelu) {
    __shared__ float v[64 * 132];
    int tid = threadIdx.x;
    int n0 = blockIdx.x * 64;
    const float4* A4 = (const float4*)Ag;
    #pragma unroll
    for (int i = 0; i < 8; ++i) {
        int fidx = i * 256 + tid;
        int r = fidx >> 5, c4 = fidx & 31;
        int n = n0 + r;
        float4 val = (n < N_NODES) ? A4[n * 32 + c4] : make_float4(0.f, 0.f, 0.f, 0.f);
        *(float4*)&v[r * 132 + c4 * 4] = val;
    }
    __syncthreads();

    int fg = tid & 15, ngp = tid >> 4;
    const float4* Wt4 = (const float4*)Wt;
    float acc[4][8];
    #pragma unroll
    for (int i = 0; i < 4; ++i)
        #pragma unroll
        for (int j = 0; j < 8; ++j) acc[i][j] = 0.f;

    #pragma unroll 4
    for (int k = 0; k < 128; ++k) {
        float4 w0 = Wt4[k * 32 + fg];
        float4 w1 = Wt4[k * 32 + 16 + fg];
        float vv[4];
        #pragma unroll
        for (int i = 0; i < 4; ++i) vv[i] = v[(ngp * 4 + i) * 132 + k];
        #pragma unroll
        for (int i = 0; i < 4; ++i) {
            acc[i][0] += vv[i] * w0.x; acc[i][1] += vv[i] * w0.y;
            acc[i][2] += vv[i] * w0.z; acc[i][3] += vv[i] * w0.w;
            acc[i][4] += vv[i] * w1.x; acc[i][5] += vv[i] * w1.y;
            acc[i][6] += vv[i] * w1.z; acc[i][7] += vv[i] * w1.w;
        }
    }

    float4 ba = ((const float4*)bias)[fg];
    float4 bb = ((const float4*)bias)[16 + fg];
    #pragma unroll
    for (int i = 0; i < 4; ++i) {
        int n = n0 + ngp * 4 + i;
        if (n >= N_NODES) continue;
        float o0[4] = {acc[i][0] + ba.x, acc[i][1] + ba.y, acc[i][2] + ba.z, acc[i][3] + ba.w};
        float o1[4] = {acc[i][4] + bb.x, acc[i][5] + bb.y, acc[i][6] + bb.z, acc[i][7] + bb.w};
        if (doRelu) {
            #pragma unroll
            for (int q = 0; q < 4; ++q) { o0[q] = fmaxf(o0[q], 0.f); o1[q] = fmaxf(o1[q], 0.f); }
        }
        ushort4 p0, p1;
        p0.x = f2b(o0[0]); p0.y = f2b(o0[1]); p0.z = f2b(o0[2]); p0.w = f2b(o0[3]);
        p1.x = f2b(o1[0]); p1.y = f2b(o1[1]); p1.z = f2b(o1[2]); p1.w = f2b(o1[3]);
        Hb[n * 32 + fg] = p0;
        Hb[n * 32 + 16 + fg] = p1;
    }
}

// ---------- pooling + classifier ----------
__device__ __forceinline__ int lower_bound_i(const int* a, int n, int val) {
    int lo = 0, hi = n;
    while (lo < hi) {
        int mid = (lo + hi) >> 1;
        if (a[mid] < val) lo = mid + 1; else hi = mid;
    }
    return lo;
}

__global__ __launch_bounds__(256) void pool_kernel(const uint4* __restrict__ Hb,
                                                   const int* __restrict__ batch,
                                                   const float* __restrict__ Wg,
                                                   const float* __restrict__ bg,
                                                   float* __restrict__ out) {
    __shared__ float p[16 * 128];
    __shared__ float pooled[128];
    int g = blockIdx.x, tid = threadIdx.x;
    int c = tid & 15, r = tid >> 4;
    int lo = lower_bound_i(batch, N_NODES, g);
    int hi = lower_bound_i(batch, N_NODES, g + 1);
    float acc[8] = {0, 0, 0, 0, 0, 0, 0, 0};
    for (int i = lo + r; i < hi; i += 16) addbf(acc, Hb[i * 16 + c]);
    #pragma unroll
    for (int k = 0; k < 8; ++k) p[r * 128 + c * 8 + k] = acc[k];
    __syncthreads();
    if (tid < 128) {
        float s = 0.f;
        #pragma unroll
        for (int q = 0; q < 16; ++q) s += p[q * 128 + tid];
        pooled[tid] = s / fmaxf((float)(hi - lo), 1.0f);
    }
    __syncthreads();
    if (tid < 10) {
        float s = bg[tid];
        #pragma unroll 4
        for (int k = 0; k < 128; ++k) s += pooled[k] * Wg[tid * 128 + k];
        out[g * 10 + tid] = s;
    }
}

// ---------- launch ----------
extern "C" void kernel_launch(void* const* d_in, const int* in_sizes, int n_in,
                              void* d_out, int out_size, void* d_ws, size_t ws_size,
                              hipStream_t stream) {
    const float* x   = (const float*)d_in[0];
    const int*   ei  = (const int*)d_in[1];
    const int*   bat = (const int*)d_in[2];
    const float* W0  = (const float*)d_in[3];
    const float* b0  = (const float*)d_in[4];
    const float* W1  = (const float*)d_in[5];
    const float* b1  = (const float*)d_in[6];
    const float* W2  = (const float*)d_in[7];
    const float* b2  = (const float*)d_in[8];
    const float* Wg  = (const float*)d_in[9];
    const float* bg  = (const float*)d_in[10];
    float* out = (float*)d_out;

    const int* src = ei;
    const int* dst = ei + N_EDGES;

    char* w = (char*)d_ws;
    float*  A       = (float*)(w);                       // 51,200,000 B fp32 accum
    ushort* Hb      = (ushort*)(w + 51200000);           // 25,600,000 B bf16 activations (layers 0,1 + input)
    char*   regionR = w + 76800000;                      // 25,600,000 B: pairs (CSR phase) then H2b
    int2*   pairs   = (int2*)regionR;                    // 12,800,000 B
    ushort* H2b     = (ushort*)regionR;                  // 25,600,000 B (layer-2 output)
    int*    srclist = (int*)(w + 102400000);             // 6,400,000 B
    int*    off     = (int*)(w + 108800000);             // 400,016 B
    float*  Wt0     = (float*)(w + 109200016);
    float*  Wt1     = Wt0 + 16384;
    float*  Wt2     = Wt1 + 16384;
    int*    gcnt    = (int*)(w + 109396624);             // NBUCK ints
    int*    boff    = gcnt + NBUCK + 1;                  // NBUCK+1 ints
    int*    gcur    = boff + NBUCK + 2;                  // NBUCK ints

    hipMemsetAsync(gcnt, 0, NBUCK * sizeof(int), stream);

    // CSR build
    bucket_hist<<<NB_BIN, 256, 0, stream>>>(dst, gcnt);
    bucket_scan<<<1, 512, 0, stream>>>(gcnt, boff, gcur, off);
    bucket_scatter<<<NB_BIN, 256, 0, stream>>>(src, dst, gcur, pairs);
    bucket_fine<<<NBUCK, 256, 0, stream>>>(pairs, boff, off, srclist);

    // input -> bf16 mirror
    convert_bf16<<<(N_NODES * 16 + 255) / 256, 256, 0, stream>>>((const float4*)x, (uint4*)Hb);

    // weight transposes
    transpose_kernel<<<128, 128, 0, stream>>>(W0, Wt0);
    transpose_kernel<<<128, 128, 0, stream>>>(W1, Wt1);
    transpose_kernel<<<128, 128, 0, stream>>>(W2, Wt2);

    int aggGrid  = (N_NODES * 16 + 255) / 256;
    int gemmGrid = (N_NODES + 63) / 64;

    // layer 0
    agg_bf16<<<aggGrid, 256, 0, stream>>>((const uint4*)Hb, A, off, srclist);
    gemm_kernel<<<gemmGrid, 256, 0, stream>>>(A, Wt0, b0, (ushort4*)Hb, 1);
    // layer 1
    agg_bf16<<<aggGrid, 256, 0, stream>>>((const uint4*)Hb, A, off, srclist);
    gemm_kernel<<<gemmGrid, 256, 0, stream>>>(A, Wt1, b1, (ushort4*)Hb, 1);
    // layer 2
    agg_bf16<<<aggGrid, 256, 0, stream>>>((const uint4*)Hb, A, off, srclist);
    gemm_kernel<<<gemmGrid, 256, 0, stream>>>(A, Wt2, b2, (ushort4*)H2b, 0);

    // pool + classifier
    pool_kernel<<<N_GRAPHS, 256, 0, stream>>>((const uint4*)H2b, bat, Wg, bg, out);
}

// Round 3
// 345.556 us; speedup vs baseline: 2.7213x; 1.3869x over previous
//
#include <hip/hip_runtime.h>

#define N_NODES 100000
#define N_EDGES 1600000
#define N_GRAPHS 512
#define NBUCK 391          // ceil(N_NODES / 256)
#define EPB 8192           // edges per block for bucket passes
#define NB_BIN ((N_EDGES + EPB - 1) / EPB)   // 196
#define CAP 5120           // LDS staging capacity per bucket

typedef _Float16 half8 __attribute__((ext_vector_type(8)));
typedef float floatx4 __attribute__((ext_vector_type(4)));

union U16 { uint4 u; half8 h; };

// ---------- CSR build: 2-level counting sort ----------

__global__ __launch_bounds__(256) void bucket_hist(const int* __restrict__ dst,
                                                   int* __restrict__ gcnt) {
    __shared__ int c[NBUCK];
    int tid = threadIdx.x;
    for (int i = tid; i < NBUCK; i += 256) c[i] = 0;
    __syncthreads();
    int e0 = blockIdx.x * EPB, e1 = min(e0 + EPB, N_EDGES);
    for (int e = e0 + tid; e < e1; e += 256) atomicAdd(&c[dst[e] >> 8], 1);
    __syncthreads();
    for (int i = tid; i < NBUCK; i += 256) { int v = c[i]; if (v) atomicAdd(&gcnt[i], v); }
}

__global__ __launch_bounds__(512) void bucket_scan(const int* __restrict__ gcnt,
                                                   int* __restrict__ boff,
                                                   int* __restrict__ gcur,
                                                   int* __restrict__ off) {
    __shared__ int ws[8];
    int tid = threadIdx.x;
    int v = (tid < NBUCK) ? gcnt[tid] : 0;
    int lane = tid & 63, w = tid >> 6;
    int incl = v;
    #pragma unroll
    for (int s = 1; s < 64; s <<= 1) { int y = __shfl_up(incl, s, 64); if (lane >= s) incl += y; }
    if (lane == 63) ws[w] = incl;
    __syncthreads();
    if (tid < 8) {
        int t = ws[tid];
        #pragma unroll
        for (int s = 1; s < 8; s <<= 1) { int y = __shfl_up(t, s, 64); if (tid >= s) t += y; }
        ws[tid] = t;
    }
    __syncthreads();
    int excl = (w ? ws[w - 1] : 0) + incl - v;
    if (tid < NBUCK) { boff[tid] = excl; gcur[tid] = excl; }
    if (tid == NBUCK - 1) boff[NBUCK] = excl + v;
    if (tid == 0) off[N_NODES] = N_EDGES;
}

__global__ __launch_bounds__(256) void bucket_scatter(const int* __restrict__ src,
                                                      const int* __restrict__ dst,
                                                      int* __restrict__ gcur,
                                                      int2* __restrict__ pairs) {
    __shared__ int cnt[NBUCK];
    __shared__ int base[NBUCK];
    int tid = threadIdx.x;
    for (int i = tid; i < NBUCK; i += 256) cnt[i] = 0;
    __syncthreads();
    int e0 = blockIdx.x * EPB, e1 = min(e0 + EPB, N_EDGES);
    for (int e = e0 + tid; e < e1; e += 256) atomicAdd(&cnt[dst[e] >> 8], 1);
    __syncthreads();
    for (int i = tid; i < NBUCK; i += 256) {
        int v = cnt[i];
        base[i] = v ? atomicAdd(&gcur[i], v) : 0;
        cnt[i] = 0;
    }
    __syncthreads();
    for (int e = e0 + tid; e < e1; e += 256) {
        int d = dst[e], b = d >> 8;
        int r = atomicAdd(&cnt[b], 1);
        pairs[base[b] + r] = make_int2(src[e], d);
    }
}

__global__ __launch_bounds__(256) void bucket_fine(const int2* __restrict__ pairs,
                                                   const int* __restrict__ boff,
                                                   int* __restrict__ off,
                                                   int* __restrict__ srclist) {
    __shared__ int ncnt[256];
    __shared__ int ws[4];
    __shared__ int stage[CAP];
    int tid = threadIdx.x, b = blockIdx.x;
    int eLo = boff[b], eHi = boff[b + 1], m = eHi - eLo;
    ncnt[tid] = 0;
    __syncthreads();
    for (int t = tid; t < m; t += 256) {
        int2 p = pairs[eLo + t];
        atomicAdd(&ncnt[p.y & 255], 1);
    }
    __syncthreads();
    int v = ncnt[tid];
    int lane = tid & 63, w = tid >> 6;
    int incl = v;
    #pragma unroll
    for (int s = 1; s < 64; s <<= 1) { int y = __shfl_up(incl, s, 64); if (lane >= s) incl += y; }
    if (lane == 63) ws[w] = incl;
    __syncthreads();
    if (tid < 4) {
        int t = ws[tid];
        #pragma unroll
        for (int s = 1; s < 4; s <<= 1) { int y = __shfl_up(t, s, 64); if (tid >= s) t += y; }
        ws[tid] = t;
    }
    __syncthreads();
    int excl = (w ? ws[w - 1] : 0) + incl - v;
    int n = (b << 8) + tid;
    if (n < N_NODES) off[n] = eLo + excl;
    __syncthreads();
    ncnt[tid] = excl;   // becomes cursor
    __syncthreads();
    for (int t = tid; t < m; t += 256) {
        int2 p = pairs[eLo + t];
        int r = atomicAdd(&ncnt[p.y & 255], 1);
        if (r < CAP) stage[r] = p.x;
        else srclist[eLo + r] = p.x;
    }
    __syncthreads();
    int lim = m < CAP ? m : CAP;
    for (int t = tid; t < lim; t += 256) srclist[eLo + t] = stage[t];
}

// ---------- fp32 -> fp16 convert (x -> Xh) ----------
__global__ __launch_bounds__(256) void convert_f16(const float4* __restrict__ X4,
                                                   uint4* __restrict__ Xh) {
    int t = blockIdx.x * 256 + threadIdx.x;
    if (t >= N_NODES * 16) return;
    float4 a = X4[t * 2], b = X4[t * 2 + 1];
    U16 o;
    o.h[0] = (_Float16)a.x; o.h[1] = (_Float16)a.y;
    o.h[2] = (_Float16)a.z; o.h[3] = (_Float16)a.w;
    o.h[4] = (_Float16)b.x; o.h[5] = (_Float16)b.y;
    o.h[6] = (_Float16)b.z; o.h[7] = (_Float16)b.w;
    Xh[t] = o.u;
}

// ---------- pack W into MFMA B-fragment order ----------
// Bpack[layer][c(4)][f(8)][lane(64)][j(8)] = W[f*16 + (lane&15)][c*32 + (lane>>4)*8 + j]
__global__ __launch_bounds__(64) void pack_w(const float* __restrict__ W0,
                                             const float* __restrict__ W1,
                                             const float* __restrict__ W2,
                                             uint4* __restrict__ Bp) {
    int b = blockIdx.x;             // 0..95
    int layer = b >> 5;
    int r = b & 31;
    int c = r >> 3, f = r & 7;
    const float* W = (layer == 0) ? W0 : (layer == 1) ? W1 : W2;
    int l = threadIdx.x;
    int col = f * 16 + (l & 15);
    int k0 = c * 32 + (l >> 4) * 8;
    U16 o;
    #pragma unroll
    for (int j = 0; j < 8; ++j) o.h[j] = (_Float16)W[col * 128 + k0 + j];
    Bp[layer * 2048 + (c * 8 + f) * 64 + l] = o.u;
}

// ---------- pull aggregation (fp16 gather + fp16 pk accum): A[n] = X[n] + sum_j X[src_j] ----------
__global__ __launch_bounds__(256) void agg_f16(const uint4* __restrict__ Xh,
                                               uint4* __restrict__ Ah,
                                               const int* __restrict__ off,
                                               const int* __restrict__ srclist) {
    int t = blockIdx.x * 256 + threadIdx.x;
    int n = t >> 4, c = t & 15;
    if (n >= N_NODES) return;
    int j0 = off[n], j1 = off[n + 1];
    U16 acc; acc.u = Xh[n * 16 + c];       // own row (GIN eps=0)
    half8 a = acc.h;
    int j = j0;
    for (; j + 3 < j1; j += 4) {
        int s0 = srclist[j], s1 = srclist[j + 1], s2 = srclist[j + 2], s3 = srclist[j + 3];
        U16 v0, v1, v2, v3;
        v0.u = Xh[s0 * 16 + c];
        v1.u = Xh[s1 * 16 + c];
        v2.u = Xh[s2 * 16 + c];
        v3.u = Xh[s3 * 16 + c];
        a += v0.h; a += v1.h; a += v2.h; a += v3.h;
    }
    for (; j < j1; ++j) {
        U16 v; v.u = Xh[srclist[j] * 16 + c];
        a += v.h;
    }
    U16 o; o.h = a;
    Ah[n * 16 + c] = o.u;
}

// ---------- MFMA GEMM: H[n] = act(A[n] @ W.T + b) ----------
// block 256 = 4 waves; each wave: 32 rows x 128 cols; no LDS, no barriers.
__global__ __launch_bounds__(256) void gemm_mfma(const _Float16* __restrict__ Ah,
                                                 const uint4* __restrict__ Bp,
                                                 const float* __restrict__ bias,
                                                 _Float16* __restrict__ H, int doRelu) {
    int tid = threadIdx.x;
    int wid = tid >> 6, lane = tid & 63;
    int nbase = blockIdx.x * 128 + wid * 32;
    int lrow = lane & 15;
    int lk = (lane >> 4) * 8;
    int row0 = min(nbase + lrow, N_NODES - 1);
    int row1 = min(nbase + 16 + lrow, N_NODES - 1);

    floatx4 acc[2][8];
    #pragma unroll
    for (int r = 0; r < 2; ++r)
        #pragma unroll
        for (int f = 0; f < 8; ++f) acc[r][f] = (floatx4)0.f;

    #pragma unroll
    for (int c = 0; c < 4; ++c) {
        U16 a0, a1;
        a0.u = *(const uint4*)(Ah + row0 * 128 + c * 32 + lk);
        a1.u = *(const uint4*)(Ah + row1 * 128 + c * 32 + lk);
        #pragma unroll
        for (int f = 0; f < 8; ++f) {
            U16 b; b.u = Bp[(c * 8 + f) * 64 + lane];
            acc[0][f] = __builtin_amdgcn_mfma_f32_16x16x32_f16(a0.h, b.h, acc[0][f], 0, 0, 0);
            acc[1][f] = __builtin_amdgcn_mfma_f32_16x16x32_f16(a1.h, b.h, acc[1][f], 0, 0, 0);
        }
    }

    int colb = lane & 15;
    int rq = (lane >> 4) * 4;
    #pragma unroll
    for (int f = 0; f < 8; ++f) {
        float bv = bias[f * 16 + colb];
        #pragma unroll
        for (int r = 0; r < 2; ++r) {
            #pragma unroll
            for (int q = 0; q < 4; ++q) {
                int row = nbase + r * 16 + rq + q;
                if (row < N_NODES) {
                    float v = acc[r][f][q] + bv;
                    if (doRelu) v = fmaxf(v, 0.f);
                    H[row * 128 + f * 16 + colb] = (_Float16)v;
                }
            }
        }
    }
}

// ---------- pooling + classifier ----------
__device__ __forceinline__ int lower_bound_i(const int* a, int n, int val) {
    int lo = 0, hi = n;
    while (lo < hi) {
        int mid = (lo + hi) >> 1;
        if (a[mid] < val) lo = mid + 1; else hi = mid;
    }
    return lo;
}

__global__ __launch_bounds__(256) void pool_kernel(const uint4* __restrict__ Hh,
                                                   const int* __restrict__ batch,
                                                   const float* __restrict__ Wg,
                                                   const float* __restrict__ bg,
                                                   float* __restrict__ out) {
    __shared__ float p[16 * 128];
    __shared__ float pooled[128];
    int g = blockIdx.x, tid = threadIdx.x;
    int c = tid & 15, r = tid >> 4;
    int lo = lower_bound_i(batch, N_NODES, g);
    int hi = lower_bound_i(batch, N_NODES, g + 1);
    float acc[8] = {0, 0, 0, 0, 0, 0, 0, 0};
    for (int i = lo + r; i < hi; i += 16) {
        U16 v; v.u = Hh[i * 16 + c];
        #pragma unroll
        for (int k = 0; k < 8; ++k) acc[k] += (float)v.h[k];
    }
    #pragma unroll
    for (int k = 0; k < 8; ++k) p[r * 128 + c * 8 + k] = acc[k];
    __syncthreads();
    if (tid < 128) {
        float s = 0.f;
        #pragma unroll
        for (int q = 0; q < 16; ++q) s += p[q * 128 + tid];
        pooled[tid] = s / fmaxf((float)(hi - lo), 1.0f);
    }
    __syncthreads();
    if (tid < 10) {
        float s = bg[tid];
        #pragma unroll 4
        for (int k = 0; k < 128; ++k) s += pooled[k] * Wg[tid * 128 + k];
        out[g * 10 + tid] = s;
    }
}

// ---------- launch ----------
extern "C" void kernel_launch(void* const* d_in, const int* in_sizes, int n_in,
                              void* d_out, int out_size, void* d_ws, size_t ws_size,
                              hipStream_t stream) {
    const float* x   = (const float*)d_in[0];
    const int*   ei  = (const int*)d_in[1];
    const int*   bat = (const int*)d_in[2];
    const float* W0  = (const float*)d_in[3];
    const float* b0  = (const float*)d_in[4];
    const float* W1  = (const float*)d_in[5];
    const float* b1  = (const float*)d_in[6];
    const float* W2  = (const float*)d_in[7];
    const float* b2  = (const float*)d_in[8];
    const float* Wg  = (const float*)d_in[9];
    const float* bg  = (const float*)d_in[10];
    float* out = (float*)d_out;

    const int* src = ei;
    const int* dst = ei + N_EDGES;

    char* w = (char*)d_ws;
    _Float16* Ah  = (_Float16*)(w);                      // 25,600,000 B (fp16 A)
    _Float16* Hh  = (_Float16*)(w + 25600000);           // 25,600,000 B (X mirror / H0 / H1)
    char*   regionR = w + 51200000;                      // pairs (CSR) then H2
    int2*     pairs = (int2*)regionR;                    // 12,800,000 B
    _Float16* H2h   = (_Float16*)regionR;                // 25,600,000 B
    int*    srclist = (int*)(w + 76800000);              // 6,400,000 B
    int*    off     = (int*)(w + 83200000);              // 400,016 B
    uint4*  Bp      = (uint4*)(w + 83600016);            // 98,304 B (3 layers)
    int*    gcnt    = (int*)(w + 83698320);              // NBUCK ints
    int*    boff    = gcnt + NBUCK + 1;
    int*    gcur    = boff + NBUCK + 2;

    hipMemsetAsync(gcnt, 0, NBUCK * sizeof(int), stream);

    // CSR build
    bucket_hist<<<NB_BIN, 256, 0, stream>>>(dst, gcnt);
    bucket_scan<<<1, 512, 0, stream>>>(gcnt, boff, gcur, off);
    bucket_scatter<<<NB_BIN, 256, 0, stream>>>(src, dst, gcur, pairs);
    bucket_fine<<<NBUCK, 256, 0, stream>>>(pairs, boff, off, srclist);

    // input -> fp16 mirror; weights -> fragment-packed fp16
    convert_f16<<<(N_NODES * 16 + 255) / 256, 256, 0, stream>>>((const float4*)x, (uint4*)Hh);
    pack_w<<<96, 64, 0, stream>>>(W0, W1, W2, Bp);

    int aggGrid  = (N_NODES * 16 + 255) / 256;
    int gemmGrid = (N_NODES + 127) / 128;

    // layer 0
    agg_f16<<<aggGrid, 256, 0, stream>>>((const uint4*)Hh, (uint4*)Ah, off, srclist);
    gemm_mfma<<<gemmGrid, 256, 0, stream>>>(Ah, Bp, b0, Hh, 1);
    // layer 1
    agg_f16<<<aggGrid, 256, 0, stream>>>((const uint4*)Hh, (uint4*)Ah, off, srclist);
    gemm_mfma<<<gemmGrid, 256, 0, stream>>>(Ah, Bp + 2048, b1, Hh, 1);
    // layer 2
    agg_f16<<<aggGrid, 256, 0, stream>>>((const uint4*)Hh, (uint4*)Ah, off, srclist);
    gemm_mfma<<<gemmGrid, 256, 0, stream>>>(Ah, Bp + 4096, b2, H2h, 0);

    // pool + classifier
    pool_kernel<<<N_GRAPHS, 256, 0, stream>>>((const uint4*)H2h, bat, Wg, bg, out);
}